// Round 19
// baseline (286.637 us; speedup 1.0000x reference)
//
#include <hip/hip_runtime.h>
#include <math.h>

// ---------------------------------------------------------------------------
// SALAD forward, round 19: fused12 restructured as 2-pass column split
// (stage-1 cols 0..255 then 256..511; acc1[4][4]=64 regs vs 128), with
// per-pass h-half handoff (32 KB LDS union) and stage-2 K-half partial
// accumulation into persistent acc2. LDS 40 KiB/block; launch_bounds(256,3)
// targets 3 blocks/CU = 12 waves (was 8) for +50% latency hiding.
// Arithmetic order per output element identical -> absmax unchanged.
// Everything else = round 18 (minus the neutral koff de-phasing). 4 launches.
// B=64, C=768, N=1024, HID=512, L=128, M=64, G=256.
// ---------------------------------------------------------------------------

#define B_SZ   64
#define C_IN   768
#define N_LOC  1024
#define HID    512
#define L_DIM  128
#define M_DIM  64
#define G_DIM  256
#define OUTD   (G_DIM + L_DIM * M_DIM)   // 8448

typedef unsigned short u16;
typedef __bf16 bf16x8 __attribute__((ext_vector_type(8)));
typedef float f32x4 __attribute__((ext_vector_type(4)));

typedef const __attribute__((address_space(1))) void* gptr_t;
typedef __attribute__((address_space(3))) void* sptr_t;

__device__ __forceinline__ void load_lds16(const void* g, void* l) {
    __builtin_amdgcn_global_load_lds((gptr_t)g, (sptr_t)l, 16, 0, 0);
}

__device__ __forceinline__ u16 f2bf(float f) {  // round-to-nearest-even
    unsigned u = __float_as_uint(f);
    u += 0x7fffu + ((u >> 16) & 1u);
    return (u16)(u >> 16);
}
__device__ __forceinline__ float bf2f(u16 h) {
    return __uint_as_float(((unsigned)h) << 16);
}

__device__ __forceinline__ float waveReduceSum(float v) {
#pragma unroll
    for (int off = 32; off > 0; off >>= 1) v += __shfl_xor(v, off, 64);
    return v;
}

// ---------------------------------------------------------------------------
// setup: blocks 0..431 = weight pack (W1 -> [kchunk][c][8], W2 -> [k2][kc][c][8]);
//        blocks 432..943 = token MLP stage 1 (hidb).
// ---------------------------------------------------------------------------
__global__ __launch_bounds__(256) void setup_kernel(
        const float* __restrict__ cw1, const float* __restrict__ sw1,
        const float* __restrict__ cw2, const float* __restrict__ sw2,
        u16* __restrict__ cw1p, u16* __restrict__ sw1p,
        u16* __restrict__ cw2p, u16* __restrict__ sw2p,
        const float* __restrict__ t, const float* __restrict__ tw1,
        const float* __restrict__ tb1, float* __restrict__ hidb) {
    __shared__ __align__(16) float tl[C_IN];
    const int blk = blockIdx.x;
    const int tid = threadIdx.x;

    if (blk < 432) {   // ---- weight pack
        const int q = blk * 256 + tid;
        const float* src;
        u16* dst;
        if (q < 98304) {                       // W1: 2 x 96 kchunk x 512 c
            int path = q / 49152, r = q % 49152;
            int kch = r / 512, c = r & 511;
            src = (path ? sw1 : cw1) + (size_t)c * C_IN + kch * 8;
            dst = (path ? sw1p : cw1p) + (size_t)r * 8;
        } else {                               // W2: f 8192 + p 4096 chunks
            int q2 = q - 98304;
            int path = (q2 >= 8192) ? 1 : 0;
            int r = q2 - (path ? 8192 : 0);
            int S2 = path ? M_DIM : L_DIM;
            int k2 = r / (4 * S2), kc = (r / S2) & 3, c = r % S2;
            src = (path ? sw2 : cw2) + (size_t)c * HID + k2 * 32 + kc * 8;
            dst = (path ? sw2p : cw2p) + (size_t)r * 8;
        }
        float4 v0 = *(const float4*)(src);
        float4 v1 = *(const float4*)(src + 4);
        *(ushort4*)(dst) = make_ushort4(f2bf(v0.x), f2bf(v0.y), f2bf(v0.z), f2bf(v0.w));
        *(ushort4*)(dst + 4) = make_ushort4(f2bf(v1.x), f2bf(v1.y), f2bf(v1.z), f2bf(v1.w));
        return;
    }

    // ---- token MLP stage 1: 512 blocks = 8 j-tiles x 64 batches
    const int by = blk - 432;
    const int j0 = (by & 7) * 64;
    const int b = by >> 3;
    const int lane = tid & 63;
    const int wave = tid >> 6;
    for (int i = tid; i < C_IN; i += 256) tl[i] = t[(size_t)b * C_IN + i];
    __syncthreads();
    for (int j = wave; j < 64; j += 4) {
        const int row = j0 + j;
        const float4* wr = (const float4*)(tw1 + (size_t)row * C_IN);
        const float4* tr = (const float4*)tl;
        float s = 0.f;
#pragma unroll
        for (int q = 0; q < 3; ++q) {
            float4 wv = wr[lane + 64 * q];
            float4 tv = tr[lane + 64 * q];
            s += wv.x * tv.x + wv.y * tv.y + wv.z * tv.z + wv.w * tv.w;
        }
        s = waveReduceSum(s);
        if (lane == 0) hidb[(size_t)b * HID + row] = fmaxf(s + tb1[row], 0.f);
    }
}

// ---------------------------------------------------------------------------
// Fused stage-1 + stage-2, 2-pass column split.
// BM=64, 256 thr = 4 waves; LDS 40 KiB: A[2][2048u16]@0, B[2][8192u16]@4096,
// handoff [32cch][64n][8]@4096 (union over B). Target 3 blocks/CU.
// Per pass P (cols 256P..+255; wave wc owns 64 cols; acc1[4][4]):
//   prologue: STG_B(0) | x(0)->xrA | AWRITE | x(1)->xrB | lgkm0 | barrier
//   tile T (buf db=T&1): ds_reads(db) | STG_B(T+1)->db^1 | XLOAD x(T+2)
//     setprio; 16 MFMA; setprio(0); AWRITE x(T+1)->db^1
//     lgkm(0); vmcnt(8) [B(T+1) drained, x(T+2) in flight]; barrier
//   handoff h-half -> LDS; syncthreads
//   stage-2 partial: k2 = 8P..8P+7, acc2 += h_half . W2half; syncthreads
// Epilogue after both passes: bias + store acc2.
// grid (16, 2, 64) XCD-bijective remap.
// ---------------------------------------------------------------------------
__global__ __launch_bounds__(256, 3) void fused12(
        const float* __restrict__ x,
        const u16* __restrict__ cw1p, const float* __restrict__ cb1,
        const u16* __restrict__ cw2p, const float* __restrict__ cb2,
        const u16* __restrict__ sw1p, const float* __restrict__ sb1,
        const u16* __restrict__ sw2p, const float* __restrict__ sb2,
        u16* __restrict__ fT, u16* __restrict__ pT) {
    __shared__ __align__(16) u16 LDSu[20480];   // 40 KiB
    const int tid = threadIdx.x;
    const int lane = tid & 63;
    const int wc = tid >> 6;   // 0..3 : 64-col quarter of the 256-col pass

    const int id = blockIdx.x + 16 * blockIdx.y + 32 * blockIdx.z;
    const int nid = (id & 7) * 256 + (id >> 3);   // 2048 % 8 == 0, bijective
    const int bx = nid & 15;
    const int path = (nid >> 4) & 1;
    const int bz = nid >> 5;
    const int r0 = bx * 64;

    const u16* W1p = path ? sw1p : cw1p;
    const float* B1 = path ? sb1 : cb1;
    const u16* W2p = path ? sw2p : cw2p;
    const float* B2 = path ? sb2 : cb2;
    u16* O2 = path ? pT : fT;
    const int S2 = path ? M_DIM : L_DIM;

    // x base for this thread's staging column: c-chunk = tid>>6, n = tid&63
    const float* xb = x + (size_t)bz * C_IN * N_LOC + r0 + (tid & 63) +
                      (size_t)(tid >> 6) * 8 * N_LOC;

    const int nk = C_IN / 32;   // 24

    // persistent stage-2 accumulator (both passes)
    f32x4 acc2[4][2];
#pragma unroll
    for (int mi = 0; mi < 4; ++mi) {
        acc2[mi][0] = (f32x4){0.f, 0.f, 0.f, 0.f};
        acc2[mi][1] = (f32x4){0.f, 0.f, 0.f, 0.f};
    }
    const int c2base = (S2 == L_DIM) ? 32 * wc : 16 * wc;
    const int cA = c2base + (lane & 15);
    const int cB = c2base + 16 + (lane & 15);   // f-path only
    const int fb0 = (lane >> 4) * S2 + cA;
    const int fb1 = (lane >> 4) * S2 + cB;

#define XLOAD(XR_, kt_)                                                        \
    do {                                                                       \
        _Pragma("unroll")                                                      \
        for (int j_ = 0; j_ < 8; ++j_)                                         \
            XR_[j_] = xb[(size_t)((kt_) * 32 + j_) * N_LOC];                   \
    } while (0)

#define AWRITE(db_, XR_)                                                       \
    do {                                                                       \
        uint4 w_;                                                              \
        w_.x = (unsigned)f2bf(XR_[0]) | ((unsigned)f2bf(XR_[1]) << 16);        \
        w_.y = (unsigned)f2bf(XR_[2]) | ((unsigned)f2bf(XR_[3]) << 16);        \
        w_.z = (unsigned)f2bf(XR_[4]) | ((unsigned)f2bf(XR_[5]) << 16);        \
        w_.w = (unsigned)f2bf(XR_[6]) | ((unsigned)f2bf(XR_[7]) << 16);        \
        *(uint4*)(&LDSu[(db_) * 2048 + tid * 8]) = w_;                         \
    } while (0)

// B half-tile: 256 cols x 32 k = 4 chunks/thread (1 KB contiguous per wave)
#define STG_B(db_, kt_)                                                        \
    do {                                                                       \
        _Pragma("unroll")                                                      \
        for (int j_ = 0; j_ < 4; ++j_)                                         \
            load_lds16(W1p + ((size_t)((kt_) * 4 + j_) * 512 + 256 * pass + tid) * 8, \
                       &LDSu[4096 + (db_) * 8192 + (j_ * 256 + tid) * 8]);     \
    } while (0)

#define AV_PTR(db_, mi_)                                                       \
    ((const bf16x8*)&LDSu[(db_) * 2048 + (lane >> 4) * 512 +                   \
                          (16 * (mi_) + (lane & 15)) * 8])
#define BW_PTR(db_, ni_)                                                       \
    ((const bf16x8*)&LDSu[4096 + (db_) * 8192 + (lane >> 4) * 2048 +           \
                          (64 * wc + 16 * (ni_) + (lane & 15)) * 8])

#define TILE_BODY(T_, DB_, XC_, XN_)                                           \
    {                                                                          \
        const int db_ = (DB_);                                                 \
        bf16x8 av[4], bw[4];                                                   \
        _Pragma("unroll")                                                      \
        for (int mi = 0; mi < 4; ++mi) av[mi] = *AV_PTR(db_, mi);              \
        _Pragma("unroll")                                                      \
        for (int ni = 0; ni < 4; ++ni) bw[ni] = *BW_PTR(db_, ni);              \
        if ((T_) + 1 < nk) STG_B(db_ ^ 1, (T_) + 1);                           \
        if ((T_) + 2 < nk) XLOAD(XN_, (T_) + 2);                               \
        __builtin_amdgcn_s_setprio(1);                                         \
        _Pragma("unroll")                                                      \
        for (int mi = 0; mi < 4; ++mi)                                         \
            _Pragma("unroll")                                                  \
            for (int ni = 0; ni < 4; ++ni)                                     \
                acc1[mi][ni] = __builtin_amdgcn_mfma_f32_16x16x32_bf16(        \
                    av[mi], bw[ni], acc1[mi][ni], 0, 0, 0);                    \
        __builtin_amdgcn_s_setprio(0);                                         \
        if ((T_) + 1 < nk) AWRITE(db_ ^ 1, XC_);                               \
        asm volatile("s_waitcnt lgkmcnt(0)" ::: "memory");                     \
        __builtin_amdgcn_sched_barrier(0);                                     \
        if ((T_) + 2 < nk)                                                     \
            asm volatile("s_waitcnt vmcnt(8)" ::: "memory");                   \
        else                                                                   \
            asm volatile("s_waitcnt vmcnt(0)" ::: "memory");                   \
        __builtin_amdgcn_s_barrier();                                          \
    }

    float xrA[8], xrB[8];

    for (int pass = 0; pass < 2; ++pass) {
        f32x4 acc1[4][4];
#pragma unroll
        for (int mi = 0; mi < 4; ++mi)
#pragma unroll
            for (int ni = 0; ni < 4; ++ni)
                acc1[mi][ni] = (f32x4){0.f, 0.f, 0.f, 0.f};

        // prologue: B(0); x(0)->xrA; A[0] write (reg-wait drains B(0)+x(0));
        // x(1)->xrB; drain A write; barrier.
        STG_B(0, 0);
        XLOAD(xrA, 0);
        AWRITE(0, xrA);
        XLOAD(xrB, 1);
        asm volatile("s_waitcnt lgkmcnt(0)" ::: "memory");
        __builtin_amdgcn_s_barrier();

        for (int tt = 0; tt < nk; tt += 2) {
            TILE_BODY(tt + 0, 0, xrB, xrA);
            TILE_BODY(tt + 1, 1, xrA, xrB);
        }

        // ---- handoff: bias+relu, h-half -> LDS [32 cchunk][64 n][8] @4096
        {
            float bv1[4];
#pragma unroll
            for (int ni = 0; ni < 4; ++ni)
                bv1[ni] = B1[256 * pass + 64 * wc + 16 * ni + (lane & 15)];
#pragma unroll
            for (int mi = 0; mi < 4; ++mi)
#pragma unroll
                for (int ni = 0; ni < 4; ++ni)
#pragma unroll
                    for (int rr = 0; rr < 4; ++rr) {
                        int n = 16 * mi + (lane >> 4) * 4 + rr;
                        int cl = 64 * wc + 16 * ni + (lane & 15);
                        float v = fmaxf(acc1[mi][ni][rr] + bv1[ni], 0.f);
                        LDSu[4096 + (cl >> 3) * 512 + n * 8 + (cl & 7)] = f2bf(v);
                    }
        }
        __syncthreads();

        // ---- stage-2 partial: acc2 += h_half . W2[k2 = 8*pass .. +8]
        {
            bf16x8 w0n = *(const bf16x8*)(W2p + ((size_t)(8 * pass) * 4 * S2 + fb0) * 8);
            bf16x8 w1n = {};
            if (S2 == L_DIM)
                w1n = *(const bf16x8*)(W2p + ((size_t)(8 * pass) * 4 * S2 + fb1) * 8);
            for (int k2l = 0; k2l < 8; ++k2l) {
                bf16x8 w0 = w0n, w1 = w1n;
                if (k2l < 7) {
                    const size_t kb = (size_t)(8 * pass + k2l + 1) * 4 * S2;
                    w0n = *(const bf16x8*)(W2p + (kb + fb0) * 8);
                    if (S2 == L_DIM)
                        w1n = *(const bf16x8*)(W2p + (kb + fb1) * 8);
                }
                bf16x8 a2[4];
#pragma unroll
                for (int mi = 0; mi < 4; ++mi)
                    a2[mi] = *(const bf16x8*)&LDSu[4096 +
                        (k2l * 4 + (lane >> 4)) * 512 + (16 * mi + (lane & 15)) * 8];
#pragma unroll
                for (int mi = 0; mi < 4; ++mi) {
                    acc2[mi][0] = __builtin_amdgcn_mfma_f32_16x16x32_bf16(
                        a2[mi], w0, acc2[mi][0], 0, 0, 0);
                    if (S2 == L_DIM)
                        acc2[mi][1] = __builtin_amdgcn_mfma_f32_16x16x32_bf16(
                            a2[mi], w1, acc2[mi][1], 0, 0, 0);
                }
            }
        }
        __syncthreads();   // handoff reads done before next pass overwrites B region
    }
#undef XLOAD
#undef AWRITE
#undef STG_B
#undef AV_PTR
#undef BW_PTR
#undef TILE_BODY

    // ---- epilogue: bias + store
    const float b20 = B2[cA];
    const float b21 = (S2 == L_DIM) ? B2[cB] : 0.f;
    u16* Ob = O2 + (size_t)bz * N_LOC * S2;
#pragma unroll
    for (int mi = 0; mi < 4; ++mi)
#pragma unroll
        for (int rr = 0; rr < 4; ++rr) {
            int row = r0 + 16 * mi + (lane >> 4) * 4 + rr;
            Ob[(size_t)row * S2 + cA] = f2bf(acc2[mi][0][rr] + b20);
            if (S2 == L_DIM)
                Ob[(size_t)row * S2 + cB] = f2bf(acc2[mi][1][rr] + b21);
        }
}

// ---------------------------------------------------------------------------
// Sinkhorn, linear domain: E = exp(p) cached bf16; eu/ev pure mul-add;
// P = E*eu*ev*1088 written as BF16.
// ---------------------------------------------------------------------------
__global__ __launch_bounds__(1024) void sinkhorn_kernel(const u16* __restrict__ pT,
                                                        const float* __restrict__ dust,
                                                        u16* __restrict__ PTb) {
    __shared__ u16 sp[M_DIM][N_LOC];   // holds E = exp(p), bf16
    __shared__ float eu[M_DIM + 1];
    __shared__ float ev[N_LOC];
    const int b = blockIdx.x;
    const int t = threadIdx.x;
    const int lane = t & 63;
    const int wave = t >> 6;
    const float alpha = dust[0];
    const float Ea = __expf(alpha);
    const float mu = 1.f / 1088.f;
    const float mu64 = 960.f / 1088.f;
    const float nu = 1.f / 1088.f;

    const uint4* prow = (const uint4*)(pT + ((size_t)b * N_LOC + t) * M_DIM);
#pragma unroll
    for (int q = 0; q < 8; ++q) {
        uint4 ch = prow[q];
        sp[q * 8 + 0][t] = (u16)(ch.x);
        sp[q * 8 + 1][t] = (u16)(ch.x >> 16);
        sp[q * 8 + 2][t] = (u16)(ch.y);
        sp[q * 8 + 3][t] = (u16)(ch.y >> 16);
        sp[q * 8 + 4][t] = (u16)(ch.z);
        sp[q * 8 + 5][t] = (u16)(ch.z >> 16);
        sp[q * 8 + 6][t] = (u16)(ch.w);
        sp[q * 8 + 7][t] = (u16)(ch.w >> 16);
    }
#pragma unroll
    for (int m = 0; m < M_DIM; ++m)
        sp[m][t] = f2bf(__expf(bf2f(sp[m][t])));
    ev[t] = 1.f;
    __syncthreads();

    for (int it = 0; it < 3; ++it) {
        for (int m = wave; m < M_DIM + 1; m += 16) {
            float s = 0.f;
            if (m < M_DIM) {
#pragma unroll
                for (int q = 0; q < 16; ++q) {
                    int c = lane + 64 * q;
                    s += bf2f(sp[m][c]) * ev[c];
                }
            } else {
#pragma unroll
                for (int q = 0; q < 16; ++q) {
                    int c = lane + 64 * q;
                    s += ev[c];
                }
                s *= Ea;
            }
            s = waveReduceSum(s);
            if (lane == 0) eu[m] = ((m < M_DIM) ? mu : mu64) / s;
        }
        __syncthreads();
        float s = Ea * eu[M_DIM];
#pragma unroll 8
        for (int m = 0; m < M_DIM; ++m) s += bf2f(sp[m][t]) * eu[m];
        ev[t] = nu / s;
        __syncthreads();
    }

    const float evt = ev[t] * 1088.f;
    u16* Prow = PTb + ((size_t)b * N_LOC + t) * M_DIM;
#pragma unroll
    for (int m8 = 0; m8 < M_DIM; m8 += 8) {
        unsigned v0 = f2bf(bf2f(sp[m8 + 0][t]) * eu[m8 + 0] * evt);
        unsigned v1 = f2bf(bf2f(sp[m8 + 1][t]) * eu[m8 + 1] * evt);
        unsigned v2 = f2bf(bf2f(sp[m8 + 2][t]) * eu[m8 + 2] * evt);
        unsigned v3 = f2bf(bf2f(sp[m8 + 3][t]) * eu[m8 + 3] * evt);
        unsigned v4 = f2bf(bf2f(sp[m8 + 4][t]) * eu[m8 + 4] * evt);
        unsigned v5 = f2bf(bf2f(sp[m8 + 5][t]) * eu[m8 + 5] * evt);
        unsigned v6 = f2bf(bf2f(sp[m8 + 6][t]) * eu[m8 + 6] * evt);
        unsigned v7 = f2bf(bf2f(sp[m8 + 7][t]) * eu[m8 + 7] * evt);
        uint4 w;
        w.x = v0 | (v1 << 16);
        w.y = v2 | (v3 << 16);
        w.z = v4 | (v5 << 16);
        w.w = v6 | (v7 << 16);
        *(uint4*)(Prow + m8) = w;
    }
}

// ---------------------------------------------------------------------------
// agg + final, exploiting global-norm == sqrt(65). grid (5, B), 256 thr.
//  bx<4 : agg m-split (16 m x 128 l), rm in-block, scaled write to out.
//  bx==4: token stage-2 + norm.
// ---------------------------------------------------------------------------
__global__ __launch_bounds__(256) void agg_final_kernel(
        const u16* __restrict__ fT, const u16* __restrict__ PTb,
        const float* __restrict__ hidb, const float* __restrict__ tw2,
        const float* __restrict__ tb2, float* __restrict__ out) {
    __shared__ __align__(16) float SH[9760];
    const int b = blockIdx.y;
    const int bx = blockIdx.x;
    const int tid = threadIdx.x;
    const int lane = tid & 63;
    const int wave = tid >> 6;
    const float EPS = 1e-12f;
    const float rs65 = 1.f / sqrtf(65.f);
    float* ob = out + (size_t)b * OUTD;

    if (bx == 4) {
        float* hl = SH;            // [512]
        float* tk = SH + 512;      // [256]
        float* red = SH + 768;     // [4]
        for (int i = tid; i < HID; i += 256) hl[i] = hidb[(size_t)b * HID + i];
        __syncthreads();
        for (int j = wave; j < G_DIM; j += 4) {
            const float4* wr = (const float4*)(tw2 + (size_t)j * HID);
            const float4* hr = (const float4*)hl;
            float s = 0.f;
#pragma unroll
            for (int q = 0; q < 2; ++q) {
                float4 wv = wr[lane + 64 * q];
                float4 hv = hr[lane + 64 * q];
                s += wv.x * hv.x + wv.y * hv.y + wv.z * hv.z + wv.w * hv.w;
            }
            s = waveReduceSum(s);
            if (lane == 0) tk[j] = s + tb2[j];
        }
        __syncthreads();
        const float tv = tk[tid];
        float ssl = tv * tv;
        ssl = waveReduceSum(ssl);
        if (lane == 0) red[wave] = ssl;
        __syncthreads();
        const float stok = red[0] + red[1] + red[2] + red[3];
        const float rt = rs65 / fmaxf(sqrtf(stok), EPS);
        ob[tid] = tv * rt;
        return;
    }

    // ---- agg m-split: 16 m x 128 l
    const int m0 = bx * 16;
    float* Fs = SH;                 // [64][132]
    float* Ps = SH + 8448;          // [64][20]
    float* ag = SH;                 // reuse after loop: [128][17]
    float* rm = SH + 9728;          // [16]
    const u16* fb = fT + (size_t)b * N_LOC * L_DIM;
    const u16* Pb = PTb + (size_t)b * N_LOC * M_DIM;

    const int sn = tid >> 2;          // 0..63
    const int fl = (tid & 3) * 32;    // 32 l per thread
    const int pm = (tid & 3) * 4;     // 4 m per thread
    const int tl = (tid >> 3) * 4;    // 0..124
    const int tm = (tid & 7) * 2;     // 0..14

    float acc[4][2] = {};

    for (int n0 = 0; n0 < N_LOC; n0 += 64) {
        __syncthreads();
#pragma unroll
        for (int j = 0; j < 4; ++j) {
            uint4 ld = *(const uint4*)(fb + (size_t)(n0 + sn) * L_DIM + fl + j * 8);
            float4 lo = make_float4(bf2f((u16)(ld.x)), bf2f((u16)(ld.x >> 16)),
                                    bf2f((u16)(ld.y)), bf2f((u16)(ld.y >> 16)));
            float4 hi = make_float4(bf2f((u16)(ld.z)), bf2f((u16)(ld.z >> 16)),
                                    bf2f((u16)(ld.w)), bf2f((u16)(ld.w >> 16)));
            *(float4*)&Fs[sn * 132 + fl + j * 8] = lo;
            *(float4*)&Fs[sn * 132 + fl + j * 8 + 4] = hi;
        }
        {
            uint2 ld = *(const uint2*)(Pb + (size_t)(n0 + sn) * M_DIM + m0 + pm);
            float4 v = make_float4(bf2f((u16)(ld.x)), bf2f((u16)(ld.x >> 16)),
                                   bf2f((u16)(ld.y)), bf2f((u16)(ld.y >> 16)));
            *(float4*)&Ps[sn * 20 + pm] = v;
        }
        __syncthreads();
#pragma unroll 8
        for (int nn = 0; nn < 64; ++nn) {
            float4 a = *(const float4*)&Fs[nn * 132 + tl];
            float p0 = Ps[nn * 20 + tm];
            float p1 = Ps[nn * 20 + tm + 1];
            acc[0][0] = fmaf(a.x, p0, acc[0][0]);
            acc[0][1] = fmaf(a.x, p1, acc[0][1]);
            acc[1][0] = fmaf(a.y, p0, acc[1][0]);
            acc[1][1] = fmaf(a.y, p1, acc[1][1]);
            acc[2][0] = fmaf(a.z, p0, acc[2][0]);
            acc[2][1] = fmaf(a.z, p1, acc[2][1]);
            acc[3][0] = fmaf(a.w, p0, acc[3][0]);
            acc[3][1] = fmaf(a.w, p1, acc[3][1]);
        }
    }

    __syncthreads();   // Fs/Ps dead; reuse as ag[128][17]
#pragma unroll
    for (int i = 0; i < 4; ++i) {
        ag[(tl + i) * 17 + tm] = acc[i][0];
        ag[(tl + i) * 17 + tm + 1] = acc[i][1];
    }
    __syncthreads();
    if (tid < 16) {
        float ss = 0.f;
#pragma unroll 8
        for (int l = 0; l < L_DIM; ++l) {
            float xv = ag[l * 17 + tid];
            ss = fmaf(xv, xv, ss);
        }
        rm[tid] = rs65 / fmaxf(sqrtf(ss), EPS);
    }
    __syncthreads();
    const float r0 = rm[tm];
    const float r1 = rm[tm + 1];
#pragma unroll
    for (int i = 0; i < 4; ++i) {
        ob[G_DIM + (tl + i) * M_DIM + m0 + tm] = acc[i][0] * r0;
        ob[G_DIM + (tl + i) * M_DIM + m0 + tm + 1] = acc[i][1] * r1;
    }
}

// ---------------------------------------------------------------------------
extern "C" void kernel_launch(void* const* d_in, const int* in_sizes, int n_in,
                              void* d_out, int out_size, void* d_ws, size_t ws_size,
                              hipStream_t stream) {
    const float* x    = (const float*)d_in[0];
    const float* t    = (const float*)d_in[1];
    const float* tw1  = (const float*)d_in[2];
    const float* tb1  = (const float*)d_in[3];
    const float* tw2  = (const float*)d_in[4];
    const float* tb2  = (const float*)d_in[5];
    const float* cw1  = (const float*)d_in[6];
    const float* cb1  = (const float*)d_in[7];
    const float* cw2  = (const float*)d_in[8];
    const float* cb2  = (const float*)d_in[9];
    const float* sw1  = (const float*)d_in[10];
    const float* sb1  = (const float*)d_in[11];
    const float* sw2  = (const float*)d_in[12];
    const float* sb2  = (const float*)d_in[13];
    const float* dust = (const float*)d_in[14];
    float* out = (float*)d_out;

    char* ws = (char*)d_ws;
    u16* fT    = (u16*)(ws + 100663296ull);          //  16,777,216
    u16* pT    = (u16*)(ws + 117440512ull);          //   8,388,608
    u16* cw1p  = (u16*)(ws + 125829120ull);          //     786,432
    u16* sw1p  = (u16*)(ws + 126615552ull);          //     786,432
    u16* cw2p  = (u16*)(ws + 127401984ull);          //     131,072
    u16* sw2p  = (u16*)(ws + 127533056ull);          //      65,536
    float* hidb = (float*)(ws + 127598592ull);       //     131,072
    u16* PTb   = (u16*)(ws);                         //   8,388,608 (bf16)

    setup_kernel<<<944, 256, 0, stream>>>(cw1, sw1, cw2, sw2,
                                          cw1p, sw1p, cw2p, sw2p,
                                          t, tw1, tb1, hidb);

    fused12<<<dim3(16, 2, B_SZ), 256, 0, stream>>>(
        x, cw1p, cb1, cw2p, cb2, sw1p, sb1, sw2p, sb2, fT, pT);

    sinkhorn_kernel<<<B_SZ, 1024, 0, stream>>>(pT, dust, PTb);
    agg_final_kernel<<<dim3(5, B_SZ), 256, 0, stream>>>(fT, PTb, hidb, tw2, tb2, out);
}

// Round 20
// 236.685 us; speedup vs baseline: 1.2111x; 1.2111x over previous
//
#include <hip/hip_runtime.h>
#include <math.h>

// ---------------------------------------------------------------------------
// SALAD forward, round 20: REVERT to round-18 best (237.0 us). Round-19's
// 2-pass acc-split raised occupancy to 3 blocks/CU but doubled x traffic
// (FETCH 126->265 MB) and staging work: net -22%. All axes now have terminal
// measurements; this is the measured-best configuration.
//  - fused12: BM=64/4 waves/72KiB, in-kernel A staging from x (3-deep xr
//    rotation), one barrier per K-tile, counted vmcnt(8), setprio, koff
//    de-phase, XCD-bijective remap. 2 blocks/CU.
//  - sqrt(65) exact final norm; linear-domain sinkhorn; consolidated
//    setup/agg_final. 4 launches.
// B=64, C=768, N=1024, HID=512, L=128, M=64, G=256.
// ---------------------------------------------------------------------------

#define B_SZ   64
#define C_IN   768
#define N_LOC  1024
#define HID    512
#define L_DIM  128
#define M_DIM  64
#define G_DIM  256
#define OUTD   (G_DIM + L_DIM * M_DIM)   // 8448

typedef unsigned short u16;
typedef __bf16 bf16x8 __attribute__((ext_vector_type(8)));
typedef float f32x4 __attribute__((ext_vector_type(4)));

typedef const __attribute__((address_space(1))) void* gptr_t;
typedef __attribute__((address_space(3))) void* sptr_t;

__device__ __forceinline__ void load_lds16(const void* g, void* l) {
    __builtin_amdgcn_global_load_lds((gptr_t)g, (sptr_t)l, 16, 0, 0);
}

__device__ __forceinline__ u16 f2bf(float f) {  // round-to-nearest-even
    unsigned u = __float_as_uint(f);
    u += 0x7fffu + ((u >> 16) & 1u);
    return (u16)(u >> 16);
}
__device__ __forceinline__ float bf2f(u16 h) {
    return __uint_as_float(((unsigned)h) << 16);
}

__device__ __forceinline__ float waveReduceSum(float v) {
#pragma unroll
    for (int off = 32; off > 0; off >>= 1) v += __shfl_xor(v, off, 64);
    return v;
}

// ---------------------------------------------------------------------------
// setup: blocks 0..431 = weight pack (W1 -> [kchunk][c][8], W2 -> [k2][kc][c][8]);
//        blocks 432..943 = token MLP stage 1 (hidb).
// ---------------------------------------------------------------------------
__global__ __launch_bounds__(256) void setup_kernel(
        const float* __restrict__ cw1, const float* __restrict__ sw1,
        const float* __restrict__ cw2, const float* __restrict__ sw2,
        u16* __restrict__ cw1p, u16* __restrict__ sw1p,
        u16* __restrict__ cw2p, u16* __restrict__ sw2p,
        const float* __restrict__ t, const float* __restrict__ tw1,
        const float* __restrict__ tb1, float* __restrict__ hidb) {
    __shared__ __align__(16) float tl[C_IN];
    const int blk = blockIdx.x;
    const int tid = threadIdx.x;

    if (blk < 432) {   // ---- weight pack
        const int q = blk * 256 + tid;
        const float* src;
        u16* dst;
        if (q < 98304) {                       // W1: 2 x 96 kchunk x 512 c
            int path = q / 49152, r = q % 49152;
            int kch = r / 512, c = r & 511;
            src = (path ? sw1 : cw1) + (size_t)c * C_IN + kch * 8;
            dst = (path ? sw1p : cw1p) + (size_t)r * 8;
        } else {                               // W2: f 8192 + p 4096 chunks
            int q2 = q - 98304;
            int path = (q2 >= 8192) ? 1 : 0;
            int r = q2 - (path ? 8192 : 0);
            int S2 = path ? M_DIM : L_DIM;
            int k2 = r / (4 * S2), kc = (r / S2) & 3, c = r % S2;
            src = (path ? sw2 : cw2) + (size_t)c * HID + k2 * 32 + kc * 8;
            dst = (path ? sw2p : cw2p) + (size_t)r * 8;
        }
        float4 v0 = *(const float4*)(src);
        float4 v1 = *(const float4*)(src + 4);
        *(ushort4*)(dst) = make_ushort4(f2bf(v0.x), f2bf(v0.y), f2bf(v0.z), f2bf(v0.w));
        *(ushort4*)(dst + 4) = make_ushort4(f2bf(v1.x), f2bf(v1.y), f2bf(v1.z), f2bf(v1.w));
        return;
    }

    // ---- token MLP stage 1: 512 blocks = 8 j-tiles x 64 batches
    const int by = blk - 432;
    const int j0 = (by & 7) * 64;
    const int b = by >> 3;
    const int lane = tid & 63;
    const int wave = tid >> 6;
    for (int i = tid; i < C_IN; i += 256) tl[i] = t[(size_t)b * C_IN + i];
    __syncthreads();
    for (int j = wave; j < 64; j += 4) {
        const int row = j0 + j;
        const float4* wr = (const float4*)(tw1 + (size_t)row * C_IN);
        const float4* tr = (const float4*)tl;
        float s = 0.f;
#pragma unroll
        for (int q = 0; q < 3; ++q) {
            float4 wv = wr[lane + 64 * q];
            float4 tv = tr[lane + 64 * q];
            s += wv.x * tv.x + wv.y * tv.y + wv.z * tv.z + wv.w * tv.w;
        }
        s = waveReduceSum(s);
        if (lane == 0) hidb[(size_t)b * HID + row] = fmaxf(s + tb1[row], 0.f);
    }
}

// ---------------------------------------------------------------------------
// Fused stage-1 + stage-2 with in-kernel A staging from x (fp32), 3-deep,
// one barrier per tile, per-fill rotated K-order (round-18 best).
// grid (16, 2, 64) XCD-bijective remap; 2 blocks/CU.
// ---------------------------------------------------------------------------
__global__ __launch_bounds__(256, 2) void fused12(
        const float* __restrict__ x,
        const u16* __restrict__ cw1p, const float* __restrict__ cb1,
        const u16* __restrict__ cw2p, const float* __restrict__ cb2,
        const u16* __restrict__ sw1p, const float* __restrict__ sb1,
        const u16* __restrict__ sw2p, const float* __restrict__ sb2,
        u16* __restrict__ fT, u16* __restrict__ pT) {
    __shared__ __align__(16) u16 LDSu[36864];   // 72 KiB
    const int tid = threadIdx.x;
    const int lane = tid & 63;
    const int wc = tid >> 6;   // 0..3 : col quarter (128 cols)

    const int id = blockIdx.x + 16 * blockIdx.y + 32 * blockIdx.z;
    const int nid = (id & 7) * 256 + (id >> 3);   // 2048 % 8 == 0, bijective
    const int bx = nid & 15;
    const int path = (nid >> 4) & 1;
    const int bz = nid >> 5;
    const int r0 = bx * 64;
    const int koff = ((id >> 9) & 1) * 12;   // de-phase across dispatch fills

    const u16* W1p = path ? sw1p : cw1p;
    const float* B1 = path ? sb1 : cb1;
    const u16* W2p = path ? sw2p : cw2p;
    const float* B2 = path ? sb2 : cb2;
    u16* O2 = path ? pT : fT;
    const int S2 = path ? M_DIM : L_DIM;

    // x base for this thread's staging column: c-chunk = tid>>6, n = tid&63
    const float* xb = x + (size_t)bz * C_IN * N_LOC + r0 + (tid & 63) +
                      (size_t)(tid >> 6) * 8 * N_LOC;

    f32x4 acc1[4][8];
#pragma unroll
    for (int mi = 0; mi < 4; ++mi)
#pragma unroll
        for (int ni = 0; ni < 8; ++ni)
            acc1[mi][ni] = (f32x4){0.f, 0.f, 0.f, 0.f};

    const int nk = C_IN / 32;   // 24 (divisible by 3)

#define WRAPK(k_) ((k_) >= 24 ? (k_) - 24 : (k_))

#define XLOAD(XR_, kt_)                                                        \
    do {                                                                       \
        const int kw_ = (kt_);                                                 \
        _Pragma("unroll")                                                      \
        for (int j_ = 0; j_ < 8; ++j_)                                         \
            XR_[j_] = xb[(size_t)(kw_ * 32 + j_) * N_LOC];                     \
    } while (0)

#define AWRITE(db_, XR_)                                                       \
    do {                                                                       \
        uint4 w_;                                                              \
        w_.x = (unsigned)f2bf(XR_[0]) | ((unsigned)f2bf(XR_[1]) << 16);        \
        w_.y = (unsigned)f2bf(XR_[2]) | ((unsigned)f2bf(XR_[3]) << 16);        \
        w_.z = (unsigned)f2bf(XR_[4]) | ((unsigned)f2bf(XR_[5]) << 16);        \
        w_.w = (unsigned)f2bf(XR_[6]) | ((unsigned)f2bf(XR_[7]) << 16);        \
        *(uint4*)(&LDSu[(db_) * 2048 + tid * 8]) = w_;                         \
    } while (0)

#define STG_B(db_, kt_)                                                        \
    do {                                                                       \
        const int kw_ = (kt_);                                                 \
        _Pragma("unroll")                                                      \
        for (int j_ = 0; j_ < 8; ++j_)                                         \
            load_lds16(W1p + (size_t)kw_ * 16384 + (size_t)(j_ * 256 + tid) * 8, \
                       &LDSu[4096 + (db_) * 16384 + (j_ * 256 + tid) * 8]);    \
    } while (0)

#define AV_PTR(db_, mi_)                                                       \
    ((const bf16x8*)&LDSu[(db_) * 2048 + (lane >> 4) * 512 +                   \
                          (16 * (mi_) + (lane & 15)) * 8])
#define BW_PTR(db_, ni_)                                                       \
    ((const bf16x8*)&LDSu[4096 + (db_) * 16384 + (lane >> 4) * 4096 +          \
                          (128 * wc + 16 * (ni_) + (lane & 15)) * 8])

#define TILE_BODY(T_, DB_, XC_, XN_)                                           \
    {                                                                          \
        const int db_ = (DB_);                                                 \
        bf16x8 av[4], bw[8];                                                   \
        _Pragma("unroll")                                                      \
        for (int mi = 0; mi < 4; ++mi) av[mi] = *AV_PTR(db_, mi);              \
        _Pragma("unroll")                                                      \
        for (int ni = 0; ni < 8; ++ni) bw[ni] = *BW_PTR(db_, ni);              \
        if ((T_) + 1 < nk) STG_B(db_ ^ 1, WRAPK((T_) + 1 + koff));             \
        if ((T_) + 3 < nk) XLOAD(XN_, WRAPK((T_) + 3 + koff));                 \
        __builtin_amdgcn_s_setprio(1);                                         \
        _Pragma("unroll")                                                      \
        for (int mi = 0; mi < 4; ++mi)                                         \
            _Pragma("unroll")                                                  \
            for (int ni = 0; ni < 8; ++ni)                                     \
                acc1[mi][ni] = __builtin_amdgcn_mfma_f32_16x16x32_bf16(        \
                    av[mi], bw[ni], acc1[mi][ni], 0, 0, 0);                    \
        __builtin_amdgcn_s_setprio(0);                                         \
        if ((T_) + 1 < nk) AWRITE(db_ ^ 1, XC_);                               \
        asm volatile("s_waitcnt lgkmcnt(0)" ::: "memory");                     \
        __builtin_amdgcn_sched_barrier(0);                                     \
        if ((T_) + 3 < nk)                                                     \
            asm volatile("s_waitcnt vmcnt(8)" ::: "memory");                   \
        else                                                                   \
            asm volatile("s_waitcnt vmcnt(0)" ::: "memory");                   \
        __builtin_amdgcn_s_barrier();                                          \
    }

    float xr0[8], xr1[8], xr2[8];

    // prologue (all tiles rotated by koff):
    STG_B(0, koff);
    XLOAD(xr2, koff);
    AWRITE(0, xr2);                 // reg-wait drains B(koff)+x(koff)
    XLOAD(xr0, WRAPK(1 + koff));
    XLOAD(xr1, WRAPK(2 + koff));
    asm volatile("s_waitcnt lgkmcnt(0)" ::: "memory");
    __builtin_amdgcn_s_barrier();

    for (int tt = 0; tt < nk; tt += 3) {
        TILE_BODY(tt + 0, (tt + 0) & 1, xr0, xr2);
        TILE_BODY(tt + 1, (tt + 1) & 1, xr1, xr0);
        TILE_BODY(tt + 2, (tt + 2) & 1, xr2, xr1);
    }
#undef WRAPK
#undef XLOAD
#undef AWRITE
#undef STG_B
#undef AV_PTR
#undef BW_PTR
#undef TILE_BODY

    // ---- handoff: bias+relu, h -> LDS as [64 cchunk][64 n][8] bf16 (64 KiB)
    {
        float bv1[8];
#pragma unroll
        for (int ni = 0; ni < 8; ++ni)
            bv1[ni] = B1[128 * wc + 16 * ni + (lane & 15)];
#pragma unroll
        for (int mi = 0; mi < 4; ++mi)
#pragma unroll
            for (int ni = 0; ni < 8; ++ni)
#pragma unroll
                for (int rr = 0; rr < 4; ++rr) {
                    int n = 16 * mi + (lane >> 4) * 4 + rr;
                    int c = 128 * wc + 16 * ni + (lane & 15);
                    float v = fmaxf(acc1[mi][ni][rr] + bv1[ni], 0.f);
                    LDSu[(c >> 3) * 512 + n * 8 + (c & 7)] = f2bf(v);
                }
    }
    __syncthreads();

    // ---- stage-2: Out2 = h . W2^T + b2, K=512 in 16 chunks of 32.
    f32x4 acc2[4][2];
#pragma unroll
    for (int mi = 0; mi < 4; ++mi) {
        acc2[mi][0] = (f32x4){0.f, 0.f, 0.f, 0.f};
        acc2[mi][1] = (f32x4){0.f, 0.f, 0.f, 0.f};
    }
    const int c2base = (S2 == L_DIM) ? 32 * wc : 16 * wc;
    const int cA = c2base + (lane & 15);
    const int cB = c2base + 16 + (lane & 15);   // f-path only
    const int fb0 = (lane >> 4) * S2 + cA;
    const int fb1 = (lane >> 4) * S2 + cB;

    bf16x8 w0n = *(const bf16x8*)(W2p + (size_t)fb0 * 8);
    bf16x8 w1n = {};
    if (S2 == L_DIM) w1n = *(const bf16x8*)(W2p + (size_t)fb1 * 8);

    for (int k2 = 0; k2 < 16; ++k2) {
        bf16x8 w0 = w0n, w1 = w1n;
        if (k2 < 15) {
            w0n = *(const bf16x8*)(W2p + ((size_t)(k2 + 1) * 4 * S2 + fb0) * 8);
            if (S2 == L_DIM)
                w1n = *(const bf16x8*)(W2p + ((size_t)(k2 + 1) * 4 * S2 + fb1) * 8);
        }
        bf16x8 a2[4];
#pragma unroll
        for (int mi = 0; mi < 4; ++mi)
            a2[mi] = *(const bf16x8*)&LDSu[(k2 * 4 + (lane >> 4)) * 512 +
                                           (16 * mi + (lane & 15)) * 8];
#pragma unroll
        for (int mi = 0; mi < 4; ++mi) {
            acc2[mi][0] = __builtin_amdgcn_mfma_f32_16x16x32_bf16(
                a2[mi], w0, acc2[mi][0], 0, 0, 0);
            if (S2 == L_DIM)
                acc2[mi][1] = __builtin_amdgcn_mfma_f32_16x16x32_bf16(
                    a2[mi], w1, acc2[mi][1], 0, 0, 0);
        }
    }

    const float b20 = B2[cA];
    const float b21 = (S2 == L_DIM) ? B2[cB] : 0.f;
    u16* Ob = O2 + (size_t)bz * N_LOC * S2;
#pragma unroll
    for (int mi = 0; mi < 4; ++mi)
#pragma unroll
        for (int rr = 0; rr < 4; ++rr) {
            int row = r0 + 16 * mi + (lane >> 4) * 4 + rr;
            Ob[(size_t)row * S2 + cA] = f2bf(acc2[mi][0][rr] + b20);
            if (S2 == L_DIM)
                Ob[(size_t)row * S2 + cB] = f2bf(acc2[mi][1][rr] + b21);
        }
}

// ---------------------------------------------------------------------------
// Sinkhorn, linear domain: E = exp(p) cached bf16; eu/ev pure mul-add;
// P = E*eu*ev*1088 written as BF16.
// ---------------------------------------------------------------------------
__global__ __launch_bounds__(1024) void sinkhorn_kernel(const u16* __restrict__ pT,
                                                        const float* __restrict__ dust,
                                                        u16* __restrict__ PTb) {
    __shared__ u16 sp[M_DIM][N_LOC];   // holds E = exp(p), bf16
    __shared__ float eu[M_DIM + 1];
    __shared__ float ev[N_LOC];
    const int b = blockIdx.x;
    const int t = threadIdx.x;
    const int lane = t & 63;
    const int wave = t >> 6;
    const float alpha = dust[0];
    const float Ea = __expf(alpha);
    const float mu = 1.f / 1088.f;
    const float mu64 = 960.f / 1088.f;
    const float nu = 1.f / 1088.f;

    const uint4* prow = (const uint4*)(pT + ((size_t)b * N_LOC + t) * M_DIM);
#pragma unroll
    for (int q = 0; q < 8; ++q) {
        uint4 ch = prow[q];
        sp[q * 8 + 0][t] = (u16)(ch.x);
        sp[q * 8 + 1][t] = (u16)(ch.x >> 16);
        sp[q * 8 + 2][t] = (u16)(ch.y);
        sp[q * 8 + 3][t] = (u16)(ch.y >> 16);
        sp[q * 8 + 4][t] = (u16)(ch.z);
        sp[q * 8 + 5][t] = (u16)(ch.z >> 16);
        sp[q * 8 + 6][t] = (u16)(ch.w);
        sp[q * 8 + 7][t] = (u16)(ch.w >> 16);
    }
#pragma unroll
    for (int m = 0; m < M_DIM; ++m)
        sp[m][t] = f2bf(__expf(bf2f(sp[m][t])));
    ev[t] = 1.f;
    __syncthreads();

    for (int it = 0; it < 3; ++it) {
        for (int m = wave; m < M_DIM + 1; m += 16) {
            float s = 0.f;
            if (m < M_DIM) {
#pragma unroll
                for (int q = 0; q < 16; ++q) {
                    int c = lane + 64 * q;
                    s += bf2f(sp[m][c]) * ev[c];
                }
            } else {
#pragma unroll
                for (int q = 0; q < 16; ++q) {
                    int c = lane + 64 * q;
                    s += ev[c];
                }
                s *= Ea;
            }
            s = waveReduceSum(s);
            if (lane == 0) eu[m] = ((m < M_DIM) ? mu : mu64) / s;
        }
        __syncthreads();
        float s = Ea * eu[M_DIM];
#pragma unroll 8
        for (int m = 0; m < M_DIM; ++m) s += bf2f(sp[m][t]) * eu[m];
        ev[t] = nu / s;
        __syncthreads();
    }

    const float evt = ev[t] * 1088.f;
    u16* Prow = PTb + ((size_t)b * N_LOC + t) * M_DIM;
#pragma unroll
    for (int m8 = 0; m8 < M_DIM; m8 += 8) {
        unsigned v0 = f2bf(bf2f(sp[m8 + 0][t]) * eu[m8 + 0] * evt);
        unsigned v1 = f2bf(bf2f(sp[m8 + 1][t]) * eu[m8 + 1] * evt);
        unsigned v2 = f2bf(bf2f(sp[m8 + 2][t]) * eu[m8 + 2] * evt);
        unsigned v3 = f2bf(bf2f(sp[m8 + 3][t]) * eu[m8 + 3] * evt);
        unsigned v4 = f2bf(bf2f(sp[m8 + 4][t]) * eu[m8 + 4] * evt);
        unsigned v5 = f2bf(bf2f(sp[m8 + 5][t]) * eu[m8 + 5] * evt);
        unsigned v6 = f2bf(bf2f(sp[m8 + 6][t]) * eu[m8 + 6] * evt);
        unsigned v7 = f2bf(bf2f(sp[m8 + 7][t]) * eu[m8 + 7] * evt);
        uint4 w;
        w.x = v0 | (v1 << 16);
        w.y = v2 | (v3 << 16);
        w.z = v4 | (v5 << 16);
        w.w = v6 | (v7 << 16);
        *(uint4*)(Prow + m8) = w;
    }
}

// ---------------------------------------------------------------------------
// agg + final, exploiting global-norm == sqrt(65). grid (5, B), 256 thr.
//  bx<4 : agg m-split (16 m x 128 l), rm in-block, scaled write to out.
//  bx==4: token stage-2 + norm.
// ---------------------------------------------------------------------------
__global__ __launch_bounds__(256) void agg_final_kernel(
        const u16* __restrict__ fT, const u16* __restrict__ PTb,
        const float* __restrict__ hidb, const float* __restrict__ tw2,
        const float* __restrict__ tb2, float* __restrict__ out) {
    __shared__ __align__(16) float SH[9760];
    const int b = blockIdx.y;
    const int bx = blockIdx.x;
    const int tid = threadIdx.x;
    const int lane = tid & 63;
    const int wave = tid >> 6;
    const float EPS = 1e-12f;
    const float rs65 = 1.f / sqrtf(65.f);
    float* ob = out + (size_t)b * OUTD;

    if (bx == 4) {
        float* hl = SH;            // [512]
        float* tk = SH + 512;      // [256]
        float* red = SH + 768;     // [4]
        for (int i = tid; i < HID; i += 256) hl[i] = hidb[(size_t)b * HID + i];
        __syncthreads();
        for (int j = wave; j < G_DIM; j += 4) {
            const float4* wr = (const float4*)(tw2 + (size_t)j * HID);
            const float4* hr = (const float4*)hl;
            float s = 0.f;
#pragma unroll
            for (int q = 0; q < 2; ++q) {
                float4 wv = wr[lane + 64 * q];
                float4 hv = hr[lane + 64 * q];
                s += wv.x * hv.x + wv.y * hv.y + wv.z * hv.z + wv.w * hv.w;
            }
            s = waveReduceSum(s);
            if (lane == 0) tk[j] = s + tb2[j];
        }
        __syncthreads();
        const float tv = tk[tid];
        float ssl = tv * tv;
        ssl = waveReduceSum(ssl);
        if (lane == 0) red[wave] = ssl;
        __syncthreads();
        const float stok = red[0] + red[1] + red[2] + red[3];
        const float rt = rs65 / fmaxf(sqrtf(stok), EPS);
        ob[tid] = tv * rt;
        return;
    }

    // ---- agg m-split: 16 m x 128 l
    const int m0 = bx * 16;
    float* Fs = SH;                 // [64][132]
    float* Ps = SH + 8448;          // [64][20]
    float* ag = SH;                 // reuse after loop: [128][17]
    float* rm = SH + 9728;          // [16]
    const u16* fb = fT + (size_t)b * N_LOC * L_DIM;
    const u16* Pb = PTb + (size_t)b * N_LOC * M_DIM;

    const int sn = tid >> 2;          // 0..63
    const int fl = (tid & 3) * 32;    // 32 l per thread
    const int pm = (tid & 3) * 4;     // 4 m per thread
    const int tl = (tid >> 3) * 4;    // 0..124
    const int tm = (tid & 7) * 2;     // 0..14

    float acc[4][2] = {};

    for (int n0 = 0; n0 < N_LOC; n0 += 64) {
        __syncthreads();
#pragma unroll
        for (int j = 0; j < 4; ++j) {
            uint4 ld = *(const uint4*)(fb + (size_t)(n0 + sn) * L_DIM + fl + j * 8);
            float4 lo = make_float4(bf2f((u16)(ld.x)), bf2f((u16)(ld.x >> 16)),
                                    bf2f((u16)(ld.y)), bf2f((u16)(ld.y >> 16)));
            float4 hi = make_float4(bf2f((u16)(ld.z)), bf2f((u16)(ld.z >> 16)),
                                    bf2f((u16)(ld.w)), bf2f((u16)(ld.w >> 16)));
            *(float4*)&Fs[sn * 132 + fl + j * 8] = lo;
            *(float4*)&Fs[sn * 132 + fl + j * 8 + 4] = hi;
        }
        {
            uint2 ld = *(const uint2*)(Pb + (size_t)(n0 + sn) * M_DIM + m0 + pm);
            float4 v = make_float4(bf2f((u16)(ld.x)), bf2f((u16)(ld.x >> 16)),
                                   bf2f((u16)(ld.y)), bf2f((u16)(ld.y >> 16)));
            *(float4*)&Ps[sn * 20 + pm] = v;
        }
        __syncthreads();
#pragma unroll 8
        for (int nn = 0; nn < 64; ++nn) {
            float4 a = *(const float4*)&Fs[nn * 132 + tl];
            float p0 = Ps[nn * 20 + tm];
            float p1 = Ps[nn * 20 + tm + 1];
            acc[0][0] = fmaf(a.x, p0, acc[0][0]);
            acc[0][1] = fmaf(a.x, p1, acc[0][1]);
            acc[1][0] = fmaf(a.y, p0, acc[1][0]);
            acc[1][1] = fmaf(a.y, p1, acc[1][1]);
            acc[2][0] = fmaf(a.z, p0, acc[2][0]);
            acc[2][1] = fmaf(a.z, p1, acc[2][1]);
            acc[3][0] = fmaf(a.w, p0, acc[3][0]);
            acc[3][1] = fmaf(a.w, p1, acc[3][1]);
        }
    }

    __syncthreads();   // Fs/Ps dead; reuse as ag[128][17]
#pragma unroll
    for (int i = 0; i < 4; ++i) {
        ag[(tl + i) * 17 + tm] = acc[i][0];
        ag[(tl + i) * 17 + tm + 1] = acc[i][1];
    }
    __syncthreads();
    if (tid < 16) {
        float ss = 0.f;
#pragma unroll 8
        for (int l = 0; l < L_DIM; ++l) {
            float xv = ag[l * 17 + tid];
            ss = fmaf(xv, xv, ss);
        }
        rm[tid] = rs65 / fmaxf(sqrtf(ss), EPS);
    }
    __syncthreads();
    const float r0 = rm[tm];
    const float r1 = rm[tm + 1];
#pragma unroll
    for (int i = 0; i < 4; ++i) {
        ob[G_DIM + (tl + i) * M_DIM + m0 + tm] = acc[i][0] * r0;
        ob[G_DIM + (tl + i) * M_DIM + m0 + tm + 1] = acc[i][1] * r1;
    }
}

// ---------------------------------------------------------------------------
extern "C" void kernel_launch(void* const* d_in, const int* in_sizes, int n_in,
                              void* d_out, int out_size, void* d_ws, size_t ws_size,
                              hipStream_t stream) {
    const float* x    = (const float*)d_in[0];
    const float* t    = (const float*)d_in[1];
    const float* tw1  = (const float*)d_in[2];
    const float* tb1  = (const float*)d_in[3];
    const float* tw2  = (const float*)d_in[4];
    const float* tb2  = (const float*)d_in[5];
    const float* cw1  = (const float*)d_in[6];
    const float* cb1  = (const float*)d_in[7];
    const float* cw2  = (const float*)d_in[8];
    const float* cb2  = (const float*)d_in[9];
    const float* sw1  = (const float*)d_in[10];
    const float* sb1  = (const float*)d_in[11];
    const float* sw2  = (const float*)d_in[12];
    const float* sb2  = (const float*)d_in[13];
    const float* dust = (const float*)d_in[14];
    float* out = (float*)d_out;

    char* ws = (char*)d_ws;
    u16* fT    = (u16*)(ws + 100663296ull);          //  16,777,216
    u16* pT    = (u16*)(ws + 117440512ull);          //   8,388,608
    u16* cw1p  = (u16*)(ws + 125829120ull);          //     786,432
    u16* sw1p  = (u16*)(ws + 126615552ull);          //     786,432
    u16* cw2p  = (u16*)(ws + 127401984ull);          //     131,072
    u16* sw2p  = (u16*)(ws + 127533056ull);          //      65,536
    float* hidb = (float*)(ws + 127598592ull);       //     131,072
    u16* PTb   = (u16*)(ws);                         //   8,388,608 (bf16)

    setup_kernel<<<944, 256, 0, stream>>>(cw1, sw1, cw2, sw2,
                                          cw1p, sw1p, cw2p, sw2p,
                                          t, tw1, tb1, hidb);

    fused12<<<dim3(16, 2, B_SZ), 256, 0, stream>>>(
        x, cw1p, cb1, cw2p, cb2, sw1p, sb1, sw2p, sb2, fT, pT);

    sinkhorn_kernel<<<B_SZ, 1024, 0, stream>>>(pT, dust, PTb);
    agg_final_kernel<<<dim3(5, B_SZ), 256, 0, stream>>>(fT, PTb, hidb, tw2, tb2, out);
}